// Round 12
// baseline (225.569 us; speedup 1.0000x reference)
//
#include <hip/hip_runtime.h>
#include <hip/hip_bf16.h>

typedef __attribute__((ext_vector_type(8))) short short8;
typedef __attribute__((ext_vector_type(4))) float f32x4;
typedef unsigned short us;

#define MFMA16(a,b,c) __builtin_amdgcn_mfma_f32_16x16x32_bf16((a),(b),(c),0,0,0)
#define LOG2E 1.4426950408889634f

static __device__ __forceinline__ us bf16r(float x){
  unsigned u = __builtin_bit_cast(unsigned, x);
  u = u + 0x7fffu + ((u >> 16) & 1u);
  return (us)(u >> 16);
}
static __device__ __forceinline__ unsigned cvtpk(float a, float b){
  unsigned r; asm("v_cvt_pk_bf16_f32 %0, %1, %2" : "=v"(r) : "v"(a), "v"(b)); return r;
}
static __device__ __forceinline__ short8 cvt8(float4 a, float4 b){
  uint4 u; u.x = cvtpk(a.x, a.y); u.y = cvtpk(a.z, a.w);
  u.z = cvtpk(b.x, b.y); u.w = cvtpk(b.z, b.w);
  return __builtin_bit_cast(short8, u);
}
static __device__ __forceinline__ float b2f(us h){
  return __builtin_bit_cast(float, (unsigned)h << 16);
}
static __device__ __forceinline__ float exp2fast(float x){
  float r; asm("v_exp_f32 %0, %1" : "=v"(r) : "v"(x)); return r;
}
static __device__ __forceinline__ float rcpfast(float x){
  float r; asm("v_rcp_f32 %0, %1" : "=v"(r) : "v"(x)); return r;
}
static __device__ __forceinline__ float fractfast(float x){
  float r; asm("v_fract_f32 %0, %1" : "=v"(r) : "v"(x)); return r;
}
// x += dpp_move(x); ctrl/row_mask are template constants (builtin needs immediates).
template<int CTRL, int RMASK>
static __device__ __forceinline__ float dpp_add(float x){
  int t = __builtin_amdgcn_update_dpp(0, __builtin_bit_cast(int, x), CTRL, RMASK, 0xf, false);
  return x + __builtin_bit_cast(float, t);
}
// 64-lane inclusive add-scan, pure VALU (6 DPP ops):
// row_shr 1/2/4/8, row_bcast:15 (rows 1,3), row_bcast:31 (rows 2,3)
static __device__ __forceinline__ float wave_iscan(float x){
  x = dpp_add<0x111, 0xf>(x);
  x = dpp_add<0x112, 0xf>(x);
  x = dpp_add<0x114, 0xf>(x);
  x = dpp_add<0x118, 0xf>(x);
  x = dpp_add<0x142, 0xa>(x);
  x = dpp_add<0x143, 0xc>(x);
  return x;
}
static __device__ __forceinline__ float lane63(float x){
  return __builtin_bit_cast(float, __builtin_amdgcn_readlane(__builtin_bit_cast(int, x), 63));
}

// ---------------- pos_emb [64d][64n] fp32 -> peT [64n][64d] bf16, pre-scaled by log2(e) ----
__global__ __launch_bounds__(256)
void transpose_pe(const float* __restrict__ pe, us* __restrict__ peT){
  const int t = threadIdx.x;
  const int n = t & 63, dq = t >> 6;
#pragma unroll
  for (int j = 0; j < 16; ++j){
    const int d = dq * 16 + j;
    peT[n * 64 + d] = bf16r(pe[d * 64 + n] * LOG2E);
  }
}

// ---------------- V bf16 [4096][1024] -> VT bf16 [b][h][64d][1024s] ----------------
__global__ __launch_bounds__(256)
void transpose_v(const us* __restrict__ Vb, us* __restrict__ VT){
  __shared__ __align__(16) us tile[64 * 72];
  const int t = threadIdx.x;
  const int stile = blockIdx.x & 15;
  const int bh = blockIdx.x >> 4;
  const int b = bh >> 4, h = bh & 15;
  const int s0 = stile << 6;
#pragma unroll
  for (int c = 0; c < 2; ++c){
    const int idx = t + (c << 8);
    const int sr = idx >> 3, cw = idx & 7;
    *(short8*)&tile[sr * 72 + cw * 8] =
        *(const short8*)(Vb + ((size_t)(b * 1024 + s0 + sr)) * 1024 + h * 64 + cw * 8);
  }
  __syncthreads();
#pragma unroll
  for (int c = 0; c < 2; ++c){
    const int idx = t + (c << 8);
    const int dr = idx >> 3, sw = idx & 7;
    short8 o;
#pragma unroll
    for (int j = 0; j < 8; ++j) o[j] = (short)tile[(sw * 8 + j) * 72 + dr];
    *(short8*)(VT + ((size_t)(bh * 64 + dr)) * 1024 + s0 + sw * 8) = o;
  }
}

// ---------------- GEMM: C[4096][1024] = A[4096][1024] @ W[1024][1024]^T + bias ----------
template<bool A_BF16, bool OUT_BF16>
__global__ __launch_bounds__(256)
void gemm3(const void* __restrict__ Av0, const void* __restrict__ Av1, const void* __restrict__ Av2,
           const float* __restrict__ W0, const float* __restrict__ W1, const float* __restrict__ W2,
           const float* __restrict__ bp0, const float* __restrict__ bp1, const float* __restrict__ bp2,
           void* __restrict__ O0, void* __restrict__ O1, void* __restrict__ O2){
  __shared__ __align__(16) us Al[128 * 64];
  __shared__ __align__(16) us Bl[128 * 64];
  const int sel = blockIdx.y;
  const void* Av   = sel == 0 ? Av0 : (sel == 1 ? Av1 : Av2);
  const float* Wm  = sel == 0 ? W0  : (sel == 1 ? W1  : W2);
  const float* bias = sel == 0 ? bp0 : (sel == 1 ? bp1 : bp2);
  void* Ov         = sel == 0 ? O0  : (sel == 1 ? O1  : O2);
  const int tid = threadIdx.x;
  const int bm = blockIdx.x & 31, bn = blockIdx.x >> 5;
  const int m0 = bm << 7, n0 = bn << 7;
  const int w = tid >> 6, l = tid & 63;
  const int lr = l & 15, lg = l >> 4;
  const int wm = (w & 1) << 6, wn = (w >> 1) << 6;
  int srow[4], scol[4], sdst[4];
#pragma unroll
  for (int c = 0; c < 4; ++c){
    const int idx = tid + (c << 8);
    const int r = idx >> 3, cw = idx & 7;
    srow[c] = r; scol[c] = cw << 3;
    sdst[c] = r * 64 + ((cw << 3) ^ ((r & 7) << 3));
  }
  const int swz = (lr & 7) << 3;
  f32x4 acc[4][4];
#pragma unroll
  for (int i = 0; i < 4; ++i)
#pragma unroll
    for (int j = 0; j < 4; ++j) acc[i][j] = (f32x4){0.f, 0.f, 0.f, 0.f};

  auto ldA = [&](int c, int k) -> short8 {
    if constexpr (A_BF16){
      return *(const short8*)((const us*)Av + (size_t)(m0 + srow[c]) * 1024 + k + scol[c]);
    } else {
      const float* p = (const float*)Av + (size_t)(m0 + srow[c]) * 1024 + k + scol[c];
      return cvt8(*(const float4*)p, *(const float4*)(p + 4));
    }
  };
  auto ldW = [&](int c, int k) -> short8 {
    const float* p = Wm + (size_t)(n0 + srow[c]) * 1024 + k + scol[c];
    return cvt8(*(const float4*)p, *(const float4*)(p + 4));
  };

  short8 av[4], bv[4];
#pragma unroll
  for (int c = 0; c < 4; ++c){ av[c] = ldA(c, 0); bv[c] = ldW(c, 0); }

  for (int k0 = 0; k0 < 1024; k0 += 64){
    __syncthreads();
#pragma unroll
    for (int c = 0; c < 4; ++c){
      *(short8*)&Al[sdst[c]] = av[c];
      *(short8*)&Bl[sdst[c]] = bv[c];
    }
    __syncthreads();
    if (k0 < 960){
#pragma unroll
      for (int c = 0; c < 4; ++c){ av[c] = ldA(c, k0 + 64); bv[c] = ldW(c, k0 + 64); }
    }
#pragma unroll
    for (int ks = 0; ks < 2; ++ks){
      short8 af[4], bfv[4];
#pragma unroll
      for (int mt = 0; mt < 4; ++mt)
        af[mt] = *(const short8*)&Al[(wm + mt * 16 + lr) * 64 + (((ks << 5) + (lg << 3)) ^ swz)];
#pragma unroll
      for (int nt = 0; nt < 4; ++nt)
        bfv[nt] = *(const short8*)&Bl[(wn + nt * 16 + lr) * 64 + (((ks << 5) + (lg << 3)) ^ swz)];
#pragma unroll
      for (int mt = 0; mt < 4; ++mt)
#pragma unroll
        for (int nt = 0; nt < 4; ++nt)
          acc[mt][nt] = MFMA16(af[mt], bfv[nt], acc[mt][nt]);
    }
  }
  float bb[4];
#pragma unroll
  for (int nt = 0; nt < 4; ++nt) bb[nt] = bias[n0 + wn + nt * 16 + lr];
#pragma unroll
  for (int mt = 0; mt < 4; ++mt)
#pragma unroll
    for (int nt = 0; nt < 4; ++nt)
#pragma unroll
      for (int r = 0; r < 4; ++r){
        const size_t m = m0 + wm + mt * 16 + lg * 4 + r;
        const size_t n = n0 + wn + nt * 16 + lr;
        const float vv = acc[mt][nt][r] + bb[nt];
        if (OUT_BF16) ((us*)Ov)[m * 1024 + n] = bf16r(vv);
        else          ((float*)Ov)[m * 1024 + n] = vv;
      }
}

// ---------------- fused CoPE attention v11: v10 + load pipelining under cap 85 ------
// Hypothesis test: stalls are global-load latency (serial load->wait->MFMA at the
// 64-VGPR cap). (256,3) -> cap 85; spend regs on depth-1 K/V prefetch + cross-chunk
// K prefetch issued before PV (PV's ~3000cyc hides the L2 latency).
__global__ __launch_bounds__(256, 3)
void cope_attn_v11(const us* __restrict__ Qb, const us* __restrict__ Kb,
                   const us* __restrict__ VT, const us* __restrict__ peT,
                   us* __restrict__ Ob){
  __shared__ __align__(16) us yl[16 * 512];   // 16 KB: li temp, then per-chunk y/P
  __shared__ float sums[16];
  const int tid = threadIdx.x;
  const int w = tid >> 6, l = tid & 63;
  const int lr = l & 15, lg = l >> 4;
  const int qt = blockIdx.x & 63;
  const int bh = blockIdx.x >> 6;
  const int b = bh >> 4, h = bh & 15;
  const int q0 = qt << 4;
  const us* Qh = Qb + ((size_t)(b * 1024 + q0)) * 1024 + h * 64;
  const us* Kh = Kb + ((size_t)(b * 1024)) * 1024 + h * 64;
  const us* Vh = VT + ((size_t)bh) * 64 * 1024;
  const float QSC = 0.125f * LOG2E;

  const short8 aq0 = *(const short8*)(Qh + (size_t)lr * 1024 + lg * 8);
  const short8 aq1 = *(const short8*)(Qh + (size_t)lr * 1024 + 32 + lg * 8);

  // 1) li[q][n] = (Q . pos_emb)*log2e ; wave w owns n-tile [16w,16w+16) -> bf16 temp
  {
    f32x4 a = (f32x4){0.f, 0.f, 0.f, 0.f};
    const short8 p0 = *(const short8*)(peT + (size_t)(w * 16 + lr) * 64 + lg * 8);
    const short8 p1 = *(const short8*)(peT + (size_t)(w * 16 + lr) * 64 + 32 + lg * 8);
    a = MFMA16(aq0, p0, a);
    a = MFMA16(aq1, p1, a);
#pragma unroll
    for (int r = 0; r < 4; ++r) yl[(lg * 4 + r) * 64 + w * 16 + lr] = bf16r(a[r]);
  }
  __syncthreads();
  // 2) per-row register tables: lane n holds {li[n] (lo16), li[n+1]-li[n] (hi16)}
  unsigned trow[4];
#pragma unroll
  for (int rr = 0; rr < 4; ++rr){
    const int row = w * 4 + rr;
    const us lov = yl[row * 64 + l];
    const us hiv = (l < 63) ? yl[row * 64 + l + 1] : lov;
    const float dif = b2f(hiv) - b2f(lov);
    trow[rr] = (unsigned)lov | ((unsigned)bf16r(dif) << 16);
  }

  float carry[4] = {0.f, 0.f, 0.f, 0.f};
  f32x4 oacc = (f32x4){0.f, 0.f, 0.f, 0.f};
  const int d0 = w * 16;
  const int psw = lr & 7;
  const int kbase = w << 7;
  const us* KwBase = Kh + (size_t)(kbase + lr) * 1024 + lg * 8;

  // cross-chunk prefetch: chunk 1's first K pair
  short8 kb0 = *(const short8*)(KwBase + (size_t)512 * 1024);
  short8 kb1 = *(const short8*)(KwBase + (size_t)512 * 1024 + 32);

  for (int c = 1; c >= 0; --c){
    const int koff = c << 9;
    __syncthreads();   // yl free (after trow setup / after prev PV)
    // 3) QK^T * QSC -> bf16 yl[16][512] granule-swizzled; wave keys [128w,128w+128)
    {
      const us* Kw = KwBase + (size_t)koff * 1024;
      short8 b0 = kb0, b1 = kb1;
      for (int t = 0; t < 8; ++t){
        short8 n0v = b0, n1v = b1;
        if (t < 7){
          const us* Kn = Kw + (size_t)((t + 1) * 16) * 1024;
          n0v = *(const short8*)(Kn);
          n1v = *(const short8*)(Kn + 32);
        }
        f32x4 a = (f32x4){0.f, 0.f, 0.f, 0.f};
        a = MFMA16(aq0, b0, a);
        a = MFMA16(aq1, b1, a);
        const int kc = kbase + t * 16 + lr;
        const unsigned p01 = cvtpk(a[0] * QSC, a[1] * QSC);
        const unsigned p23 = cvtpk(a[2] * QSC, a[3] * QSC);
        const int r0 = lg * 4;
        yl[(r0 + 0) * 512 + (((kc >> 3) ^ ((r0 + 0) & 7)) << 3) + (kc & 7)] = (us)p01;
        yl[(r0 + 1) * 512 + (((kc >> 3) ^ ((r0 + 1) & 7)) << 3) + (kc & 7)] = (us)(p01 >> 16);
        yl[(r0 + 2) * 512 + (((kc >> 3) ^ ((r0 + 2) & 7)) << 3) + (kc & 7)] = (us)p23;
        yl[(r0 + 3) * 512 + (((kc >> 3) ^ ((r0 + 3) & 7)) << 3) + (kc & 7)] = (us)(p23 >> 16);
        b0 = n0v; b1 = n1v;
      }
    }
    __syncthreads();
    // 4) CoPE + unnormalized exp2; wave w owns rows [4w,4w+4); lane owns cols [8l,8l+8)
#pragma unroll
    for (int rr = 0; rr < 4; ++rr){
      const int row = w * 4 + rr;
      const int ad = row * 512 + ((l ^ (row & 7)) << 3);
      const short8 y0 = *(const short8*)&yl[ad];
      float x[8];
#pragma unroll
      for (int j = 0; j < 8; ++j) x[j] = b2f((us)y0[j]);
      // 8 independent sigmoids (trans-pipe pipelined), then depth-3 tree prefix
      float g[8];
#pragma unroll
      for (int i = 0; i < 8; ++i) g[i] = rcpfast(1.f + exp2fast(-x[i]));
      const float a1 = g[0] + g[1];
      const float a3 = g[2] + g[3];
      const float a5 = g[4] + g[5];
      const float a7 = g[6] + g[7];
      const float b2v = g[2] + a1;
      const float b3v = a3 + a1;
      const float i4 = g[4] + b3v;
      const float i5 = a5 + b3v;
      const float i6 = g[6] + a5 + b3v;
      const float s  = a7 + a5 + b3v;     // inclusive total of this lane's 8 gates
      float pref[8];
      pref[0] = 0.f;  pref[1] = g[0]; pref[2] = a1;  pref[3] = b2v;
      pref[4] = b3v;  pref[5] = i4;   pref[6] = i5;  pref[7] = i6;
      // DPP wave scan (VALU-only) replaces bpermute shfl chain
      const float run = wave_iscan(s);
      const float T = lane63(run);
      const float base = carry[rr] + T - (run - s);   // suffix base incl. higher chunks
      carry[rr] += T;
      const unsigned tbl = trow[rr];
      float sum = 0.f;
#pragma unroll
      for (int i = 0; i < 8; ++i){
        float p = base - pref[i];
        p = __builtin_amdgcn_fmed3f(p, 0.f, 63.f);
        const int il = (int)p;
        const float wt = fractfast(p);
        const unsigned pr = (unsigned)__builtin_amdgcn_ds_bpermute(il << 2, (int)tbl);
        const float lo  = __builtin_bit_cast(float, pr << 16);
        const float dif = __builtin_bit_cast(float, pr & 0xffff0000u);
        const float e = exp2fast(x[i] + lo + wt * dif);
        x[i] = e;
        sum += e;
      }
      const float rs = lane63(wave_iscan(sum));   // row total via DPP reduce
      if (l == 0){
        if (c == 1) sums[row] = rs;
        else        sums[row] += rs;   // same lane wrote chunk 1: no race
      }
      uint4 ua;
      ua.x = cvtpk(x[0], x[1]); ua.y = cvtpk(x[2], x[3]);
      ua.z = cvtpk(x[4], x[5]); ua.w = cvtpk(x[6], x[7]);
      *(uint4*)&yl[ad] = ua;    // in place: lane writes exactly what it read
    }
    // cross-chunk prefetch: issue chunk 0's first K pair; PV below hides the latency
    if (c == 1){
      kb0 = *(const short8*)(KwBase);
      kb1 = *(const short8*)(KwBase + 32);
    }
    __syncthreads();
    // 5) PV accumulate: wave w owns d-tile [16w,16w+16), depth-1 V prefetch
    {
      const us* Vw = Vh + (size_t)(d0 + lr) * 1024 + koff + lg * 8;
      short8 vb = *(const short8*)(Vw);
      for (int ks = 0; ks < 16; ++ks){
        short8 vn = vb;
        if (ks < 15) vn = *(const short8*)(Vw + (ks + 1) * 32);
        const short8 pa = *(const short8*)&yl[lr * 512 + ((((ks << 2) + lg) ^ psw) << 3)];
        oacc = MFMA16(pa, vb, oacc);
        vb = vn;
      }
    }
  }
  __syncthreads();   // sums visible
#pragma unroll
  for (int r = 0; r < 4; ++r){
    const float inv = rcpfast(sums[lg * 4 + r]);
    Ob[((size_t)(b * 1024 + q0 + lg * 4 + r)) * 1024 + h * 64 + d0 + lr] = bf16r(oacc[r] * inv);
  }
}

extern "C" void kernel_launch(void* const* d_in, const int* in_sizes, int n_in,
                              void* d_out, int out_size, void* d_ws, size_t ws_size,
                              hipStream_t stream) {
  const float* q    = (const float*)d_in[0];
  const float* k    = (const float*)d_in[1];
  const float* v    = (const float*)d_in[2];
  const float* Wq_w = (const float*)d_in[3];
  const float* Wq_b = (const float*)d_in[4];
  const float* Wk_w = (const float*)d_in[5];
  const float* Wk_b = (const float*)d_in[6];
  const float* Wv_w = (const float*)d_in[7];
  const float* Wv_b = (const float*)d_in[8];
  const float* Wo_w = (const float*)d_in[9];
  const float* Wo_b = (const float*)d_in[10];
  const float* pe   = (const float*)d_in[11];
  float* out = (float*)d_out;

  char* W = (char*)d_ws;
  const size_t MB = (size_t)1 << 20;
  us* Qbf = (us*)(W);
  us* Kbf = (us*)(W + 8 * MB);
  us* Vbf = (us*)(W + 16 * MB);
  us* VTb = (us*)(W + 24 * MB);
  us* Obf = (us*)(W + 32 * MB);
  us* peT = (us*)(W + 40 * MB);

  transpose_pe<<<1, 256, 0, stream>>>(pe, peT);
  gemm3<false, true><<<dim3(256, 3), 256, 0, stream>>>(
      q, k, v, Wq_w, Wk_w, Wv_w, Wq_b, Wk_b, Wv_b, Qbf, Kbf, Vbf);
  transpose_v<<<1024, 256, 0, stream>>>(Vbf, VTb);
  cope_attn_v11<<<4096, 256, 0, stream>>>(Qbf, Kbf, VTb, peT, Obf);
  gemm3<true, false><<<dim3(256, 1), 256, 0, stream>>>(
      Obf, Obf, Obf, Wo_w, Wo_w, Wo_w, Wo_b, Wo_b, Wo_b, out, out, out);
}

// Round 13
// 217.232 us; speedup vs baseline: 1.0384x; 1.0384x over previous
//
#include <hip/hip_runtime.h>
#include <hip/hip_bf16.h>

typedef __attribute__((ext_vector_type(8))) short short8;
typedef __attribute__((ext_vector_type(4))) float f32x4;
typedef unsigned short us;

#define MFMA16(a,b,c) __builtin_amdgcn_mfma_f32_16x16x32_bf16((a),(b),(c),0,0,0)
#define LOG2E 1.4426950408889634f

static __device__ __forceinline__ us bf16r(float x){
  unsigned u = __builtin_bit_cast(unsigned, x);
  u = u + 0x7fffu + ((u >> 16) & 1u);
  return (us)(u >> 16);
}
static __device__ __forceinline__ unsigned cvtpk(float a, float b){
  unsigned r; asm("v_cvt_pk_bf16_f32 %0, %1, %2" : "=v"(r) : "v"(a), "v"(b)); return r;
}
static __device__ __forceinline__ short8 cvt8(float4 a, float4 b){
  uint4 u; u.x = cvtpk(a.x, a.y); u.y = cvtpk(a.z, a.w);
  u.z = cvtpk(b.x, b.y); u.w = cvtpk(b.z, b.w);
  return __builtin_bit_cast(short8, u);
}
static __device__ __forceinline__ float b2f(us h){
  return __builtin_bit_cast(float, (unsigned)h << 16);
}
static __device__ __forceinline__ float exp2fast(float x){
  float r; asm("v_exp_f32 %0, %1" : "=v"(r) : "v"(x)); return r;
}
static __device__ __forceinline__ float rcpfast(float x){
  float r; asm("v_rcp_f32 %0, %1" : "=v"(r) : "v"(x)); return r;
}
static __device__ __forceinline__ float fractfast(float x){
  float r; asm("v_fract_f32 %0, %1" : "=v"(r) : "v"(x)); return r;
}
// x += dpp_move(x); ctrl/row_mask are template constants (builtin needs immediates).
template<int CTRL, int RMASK>
static __device__ __forceinline__ float dpp_add(float x){
  int t = __builtin_amdgcn_update_dpp(0, __builtin_bit_cast(int, x), CTRL, RMASK, 0xf, false);
  return x + __builtin_bit_cast(float, t);
}
// 64-lane inclusive add-scan, pure VALU (6 DPP ops):
// row_shr 1/2/4/8, row_bcast:15 (rows 1,3), row_bcast:31 (rows 2,3)
static __device__ __forceinline__ float wave_iscan(float x){
  x = dpp_add<0x111, 0xf>(x);
  x = dpp_add<0x112, 0xf>(x);
  x = dpp_add<0x114, 0xf>(x);
  x = dpp_add<0x118, 0xf>(x);
  x = dpp_add<0x142, 0xa>(x);
  x = dpp_add<0x143, 0xc>(x);
  return x;
}
static __device__ __forceinline__ float lane63(float x){
  return __builtin_bit_cast(float, __builtin_amdgcn_readlane(__builtin_bit_cast(int, x), 63));
}

// ---------------- pos_emb [64d][64n] fp32 -> peT [64n][64d] bf16, pre-scaled by log2(e) ----
__global__ __launch_bounds__(256)
void transpose_pe(const float* __restrict__ pe, us* __restrict__ peT){
  const int t = threadIdx.x;
  const int n = t & 63, dq = t >> 6;
#pragma unroll
  for (int j = 0; j < 16; ++j){
    const int d = dq * 16 + j;
    peT[n * 64 + d] = bf16r(pe[d * 64 + n] * LOG2E);
  }
}

// ---------------- V bf16 [4096][1024] -> VT bf16 [b][h][64d][1024s] ----------------
__global__ __launch_bounds__(256)
void transpose_v(const us* __restrict__ Vb, us* __restrict__ VT){
  __shared__ __align__(16) us tile[64 * 72];
  const int t = threadIdx.x;
  const int stile = blockIdx.x & 15;
  const int bh = blockIdx.x >> 4;
  const int b = bh >> 4, h = bh & 15;
  const int s0 = stile << 6;
#pragma unroll
  for (int c = 0; c < 2; ++c){
    const int idx = t + (c << 8);
    const int sr = idx >> 3, cw = idx & 7;
    *(short8*)&tile[sr * 72 + cw * 8] =
        *(const short8*)(Vb + ((size_t)(b * 1024 + s0 + sr)) * 1024 + h * 64 + cw * 8);
  }
  __syncthreads();
#pragma unroll
  for (int c = 0; c < 2; ++c){
    const int idx = t + (c << 8);
    const int dr = idx >> 3, sw = idx & 7;
    short8 o;
#pragma unroll
    for (int j = 0; j < 8; ++j) o[j] = (short)tile[(sw * 8 + j) * 72 + dr];
    *(short8*)(VT + ((size_t)(bh * 64 + dr)) * 1024 + s0 + sw * 8) = o;
  }
}

// ---------------- GEMM: C[4096][1024] = A[4096][1024] @ W[1024][1024]^T + bias ----------
template<bool A_BF16, bool OUT_BF16>
__global__ __launch_bounds__(256)
void gemm3(const void* __restrict__ Av0, const void* __restrict__ Av1, const void* __restrict__ Av2,
           const float* __restrict__ W0, const float* __restrict__ W1, const float* __restrict__ W2,
           const float* __restrict__ bp0, const float* __restrict__ bp1, const float* __restrict__ bp2,
           void* __restrict__ O0, void* __restrict__ O1, void* __restrict__ O2){
  __shared__ __align__(16) us Al[128 * 64];
  __shared__ __align__(16) us Bl[128 * 64];
  const int sel = blockIdx.y;
  const void* Av   = sel == 0 ? Av0 : (sel == 1 ? Av1 : Av2);
  const float* Wm  = sel == 0 ? W0  : (sel == 1 ? W1  : W2);
  const float* bias = sel == 0 ? bp0 : (sel == 1 ? bp1 : bp2);
  void* Ov         = sel == 0 ? O0  : (sel == 1 ? O1  : O2);
  const int tid = threadIdx.x;
  const int bm = blockIdx.x & 31, bn = blockIdx.x >> 5;
  const int m0 = bm << 7, n0 = bn << 7;
  const int w = tid >> 6, l = tid & 63;
  const int lr = l & 15, lg = l >> 4;
  const int wm = (w & 1) << 6, wn = (w >> 1) << 6;
  int srow[4], scol[4], sdst[4];
#pragma unroll
  for (int c = 0; c < 4; ++c){
    const int idx = tid + (c << 8);
    const int r = idx >> 3, cw = idx & 7;
    srow[c] = r; scol[c] = cw << 3;
    sdst[c] = r * 64 + ((cw << 3) ^ ((r & 7) << 3));
  }
  const int swz = (lr & 7) << 3;
  f32x4 acc[4][4];
#pragma unroll
  for (int i = 0; i < 4; ++i)
#pragma unroll
    for (int j = 0; j < 4; ++j) acc[i][j] = (f32x4){0.f, 0.f, 0.f, 0.f};

  auto ldA = [&](int c, int k) -> short8 {
    if constexpr (A_BF16){
      return *(const short8*)((const us*)Av + (size_t)(m0 + srow[c]) * 1024 + k + scol[c]);
    } else {
      const float* p = (const float*)Av + (size_t)(m0 + srow[c]) * 1024 + k + scol[c];
      return cvt8(*(const float4*)p, *(const float4*)(p + 4));
    }
  };
  auto ldW = [&](int c, int k) -> short8 {
    const float* p = Wm + (size_t)(n0 + srow[c]) * 1024 + k + scol[c];
    return cvt8(*(const float4*)p, *(const float4*)(p + 4));
  };

  short8 av[4], bv[4];
#pragma unroll
  for (int c = 0; c < 4; ++c){ av[c] = ldA(c, 0); bv[c] = ldW(c, 0); }

  for (int k0 = 0; k0 < 1024; k0 += 64){
    __syncthreads();
#pragma unroll
    for (int c = 0; c < 4; ++c){
      *(short8*)&Al[sdst[c]] = av[c];
      *(short8*)&Bl[sdst[c]] = bv[c];
    }
    __syncthreads();
    if (k0 < 960){
#pragma unroll
      for (int c = 0; c < 4; ++c){ av[c] = ldA(c, k0 + 64); bv[c] = ldW(c, k0 + 64); }
    }
#pragma unroll
    for (int ks = 0; ks < 2; ++ks){
      short8 af[4], bfv[4];
#pragma unroll
      for (int mt = 0; mt < 4; ++mt)
        af[mt] = *(const short8*)&Al[(wm + mt * 16 + lr) * 64 + (((ks << 5) + (lg << 3)) ^ swz)];
#pragma unroll
      for (int nt = 0; nt < 4; ++nt)
        bfv[nt] = *(const short8*)&Bl[(wn + nt * 16 + lr) * 64 + (((ks << 5) + (lg << 3)) ^ swz)];
#pragma unroll
      for (int mt = 0; mt < 4; ++mt)
#pragma unroll
        for (int nt = 0; nt < 4; ++nt)
          acc[mt][nt] = MFMA16(af[mt], bfv[nt], acc[mt][nt]);
    }
  }
  float bb[4];
#pragma unroll
  for (int nt = 0; nt < 4; ++nt) bb[nt] = bias[n0 + wn + nt * 16 + lr];
#pragma unroll
  for (int mt = 0; mt < 4; ++mt)
#pragma unroll
    for (int nt = 0; nt < 4; ++nt)
#pragma unroll
      for (int r = 0; r < 4; ++r){
        const size_t m = m0 + wm + mt * 16 + lg * 4 + r;
        const size_t n = n0 + wn + nt * 16 + lr;
        const float vv = acc[mt][nt][r] + bb[nt];
        if (OUT_BF16) ((us*)Ov)[m * 1024 + n] = bf16r(vv);
        else          ((float*)Ov)[m * 1024 + n] = vv;
      }
}

// ---------------- fused CoPE attention v12: v10 + chunk-0 clamp fast path ------
// Keys processed high-chunk-first. If carry (gate mass of chunk 1) >= 63, every
// chunk-0 position clamps to 63 exactly -> interp == li[63]; skip gates/scan/gather
// for the whole chunk-0 row. Wave-uniform branch; exact fallback otherwise.
__global__ __launch_bounds__(256, 4)
void cope_attn_v12(const us* __restrict__ Qb, const us* __restrict__ Kb,
                   const us* __restrict__ VT, const us* __restrict__ peT,
                   us* __restrict__ Ob){
  __shared__ __align__(16) us yl[16 * 512];   // 16 KB: li temp, then per-chunk y/P
  __shared__ float sums[16];
  const int tid = threadIdx.x;
  const int w = tid >> 6, l = tid & 63;
  const int lr = l & 15, lg = l >> 4;
  const int qt = blockIdx.x & 63;
  const int bh = blockIdx.x >> 6;
  const int b = bh >> 4, h = bh & 15;
  const int q0 = qt << 4;
  const us* Qh = Qb + ((size_t)(b * 1024 + q0)) * 1024 + h * 64;
  const us* Kh = Kb + ((size_t)(b * 1024)) * 1024 + h * 64;
  const us* Vh = VT + ((size_t)bh) * 64 * 1024;
  const float QSC = 0.125f * LOG2E;

  const short8 aq0 = *(const short8*)(Qh + (size_t)lr * 1024 + lg * 8);
  const short8 aq1 = *(const short8*)(Qh + (size_t)lr * 1024 + 32 + lg * 8);

  // 1) li[q][n] = (Q . pos_emb)*log2e ; wave w owns n-tile [16w,16w+16) -> bf16 temp
  {
    f32x4 a = (f32x4){0.f, 0.f, 0.f, 0.f};
    const short8 p0 = *(const short8*)(peT + (size_t)(w * 16 + lr) * 64 + lg * 8);
    const short8 p1 = *(const short8*)(peT + (size_t)(w * 16 + lr) * 64 + 32 + lg * 8);
    a = MFMA16(aq0, p0, a);
    a = MFMA16(aq1, p1, a);
#pragma unroll
    for (int r = 0; r < 4; ++r) yl[(lg * 4 + r) * 64 + w * 16 + lr] = bf16r(a[r]);
  }
  __syncthreads();
  // 2) per-row register tables: lane n holds {li[n] (lo16), li[n+1]-li[n] (hi16)}
  unsigned trow[4];
#pragma unroll
  for (int rr = 0; rr < 4; ++rr){
    const int row = w * 4 + rr;
    const us lov = yl[row * 64 + l];
    const us hiv = (l < 63) ? yl[row * 64 + l + 1] : lov;
    const float dif = b2f(hiv) - b2f(lov);
    trow[rr] = (unsigned)lov | ((unsigned)bf16r(dif) << 16);
  }

  float carry[4] = {0.f, 0.f, 0.f, 0.f};
  f32x4 oacc = (f32x4){0.f, 0.f, 0.f, 0.f};
  const int d0 = w * 16;
  const int psw = lr & 7;

  for (int c = 1; c >= 0; --c){
    const int koff = c << 9;
    __syncthreads();   // yl free (after trow setup / after prev PV)
    // 3) QK^T * QSC -> bf16 yl[16][512] granule-swizzled; wave keys [128w,128w+128)
    {
      const int kbase = w << 7;
      const us* Kw = Kh + (size_t)(koff + kbase + lr) * 1024 + lg * 8;
      for (int t = 0; t < 8; ++t){
        const short8 b0 = *(const short8*)(Kw + (size_t)(t * 16) * 1024);
        const short8 b1 = *(const short8*)(Kw + (size_t)(t * 16) * 1024 + 32);
        f32x4 a = (f32x4){0.f, 0.f, 0.f, 0.f};
        a = MFMA16(aq0, b0, a);
        a = MFMA16(aq1, b1, a);
        const int kc = kbase + t * 16 + lr;
        const unsigned p01 = cvtpk(a[0] * QSC, a[1] * QSC);
        const unsigned p23 = cvtpk(a[2] * QSC, a[3] * QSC);
        const int r0 = lg * 4;
        yl[(r0 + 0) * 512 + (((kc >> 3) ^ ((r0 + 0) & 7)) << 3) + (kc & 7)] = (us)p01;
        yl[(r0 + 1) * 512 + (((kc >> 3) ^ ((r0 + 1) & 7)) << 3) + (kc & 7)] = (us)(p01 >> 16);
        yl[(r0 + 2) * 512 + (((kc >> 3) ^ ((r0 + 2) & 7)) << 3) + (kc & 7)] = (us)p23;
        yl[(r0 + 3) * 512 + (((kc >> 3) ^ ((r0 + 3) & 7)) << 3) + (kc & 7)] = (us)(p23 >> 16);
      }
    }
    __syncthreads();
    // 4) CoPE + unnormalized exp2; wave w owns rows [4w,4w+4); lane owns cols [8l,8l+8)
#pragma unroll
    for (int rr = 0; rr < 4; ++rr){
      const int row = w * 4 + rr;
      const int ad = row * 512 + ((l ^ (row & 7)) << 3);
      const short8 y0 = *(const short8*)&yl[ad];
      float x[8];
#pragma unroll
      for (int j = 0; j < 8; ++j) x[j] = b2f((us)y0[j]);
      float sum = 0.f;
      if (c == 0 && carry[rr] >= 63.f){
        // all chunk-0 positions clamp to 63: interp == li[row][63] uniformly
        const float li63 = b2f((us)(unsigned)__builtin_amdgcn_readlane((int)trow[rr], 63));
#pragma unroll
        for (int i = 0; i < 8; ++i){
          const float e = exp2fast(x[i] + li63);
          x[i] = e;
          sum += e;
        }
      } else {
        // 8 independent sigmoids (trans-pipe pipelined), then depth-3 tree prefix
        float g[8];
#pragma unroll
        for (int i = 0; i < 8; ++i) g[i] = rcpfast(1.f + exp2fast(-x[i]));
        const float a1 = g[0] + g[1];
        const float a3 = g[2] + g[3];
        const float a5 = g[4] + g[5];
        const float a7 = g[6] + g[7];
        const float b2v = g[2] + a1;
        const float b3v = a3 + a1;
        const float i4 = g[4] + b3v;
        const float i5 = a5 + b3v;
        const float i6 = g[6] + a5 + b3v;
        const float s  = a7 + a5 + b3v;     // inclusive total of this lane's 8 gates
        float pref[8];
        pref[0] = 0.f;  pref[1] = g[0]; pref[2] = a1;  pref[3] = b2v;
        pref[4] = b3v;  pref[5] = i4;   pref[6] = i5;  pref[7] = i6;
        // DPP wave scan (VALU-only)
        const float run = wave_iscan(s);
        const float T = lane63(run);
        const float base = carry[rr] + T - (run - s);   // suffix base incl. higher chunks
        carry[rr] += T;
        const unsigned tbl = trow[rr];
#pragma unroll
        for (int i = 0; i < 8; ++i){
          float p = base - pref[i];
          p = __builtin_amdgcn_fmed3f(p, 0.f, 63.f);
          const int il = (int)p;
          const float wt = fractfast(p);
          const unsigned pr = (unsigned)__builtin_amdgcn_ds_bpermute(il << 2, (int)tbl);
          const float lo  = __builtin_bit_cast(float, pr << 16);
          const float dif = __builtin_bit_cast(float, pr & 0xffff0000u);
          const float e = exp2fast(x[i] + lo + wt * dif);
          x[i] = e;
          sum += e;
        }
      }
      const float rs = lane63(wave_iscan(sum));   // row total via DPP reduce
      if (l == 0){
        if (c == 1) sums[row] = rs;
        else        sums[row] += rs;   // same lane wrote chunk 1: no race
      }
      uint4 ua;
      ua.x = cvtpk(x[0], x[1]); ua.y = cvtpk(x[2], x[3]);
      ua.z = cvtpk(x[4], x[5]); ua.w = cvtpk(x[6], x[7]);
      *(uint4*)&yl[ad] = ua;    // in place: lane writes exactly what it read
    }
    __syncthreads();
    // 5) PV accumulate: wave w owns d-tile [16w,16w+16)
    {
      const us* Vw = Vh + (size_t)(d0 + lr) * 1024 + koff + lg * 8;
      for (int ks = 0; ks < 16; ++ks){
        const short8 vb = *(const short8*)(Vw + ks * 32);
        const short8 pa = *(const short8*)&yl[lr * 512 + ((((ks << 2) + lg) ^ psw) << 3)];
        oacc = MFMA16(pa, vb, oacc);
      }
    }
  }
  __syncthreads();   // sums visible
#pragma unroll
  for (int r = 0; r < 4; ++r){
    const float inv = rcpfast(sums[lg * 4 + r]);
    Ob[((size_t)(b * 1024 + q0 + lg * 4 + r)) * 1024 + h * 64 + d0 + lr] = bf16r(oacc[r] * inv);
  }
}

extern "C" void kernel_launch(void* const* d_in, const int* in_sizes, int n_in,
                              void* d_out, int out_size, void* d_ws, size_t ws_size,
                              hipStream_t stream) {
  const float* q    = (const float*)d_in[0];
  const float* k    = (const float*)d_in[1];
  const float* v    = (const float*)d_in[2];
  const float* Wq_w = (const float*)d_in[3];
  const float* Wq_b = (const float*)d_in[4];
  const float* Wk_w = (const float*)d_in[5];
  const float* Wk_b = (const float*)d_in[6];
  const float* Wv_w = (const float*)d_in[7];
  const float* Wv_b = (const float*)d_in[8];
  const float* Wo_w = (const float*)d_in[9];
  const float* Wo_b = (const float*)d_in[10];
  const float* pe   = (const float*)d_in[11];
  float* out = (float*)d_out;

  char* W = (char*)d_ws;
  const size_t MB = (size_t)1 << 20;
  us* Qbf = (us*)(W);
  us* Kbf = (us*)(W + 8 * MB);
  us* Vbf = (us*)(W + 16 * MB);
  us* VTb = (us*)(W + 24 * MB);
  us* Obf = (us*)(W + 32 * MB);
  us* peT = (us*)(W + 40 * MB);

  transpose_pe<<<1, 256, 0, stream>>>(pe, peT);
  gemm3<false, true><<<dim3(256, 3), 256, 0, stream>>>(
      q, k, v, Wq_w, Wk_w, Wv_w, Wq_b, Wk_b, Wv_b, Qbf, Kbf, Vbf);
  transpose_v<<<1024, 256, 0, stream>>>(Vbf, VTb);
  cope_attn_v12<<<4096, 256, 0, stream>>>(Qbf, Kbf, VTb, peT, Obf);
  gemm3<true, false><<<dim3(256, 1), 256, 0, stream>>>(
      Obf, Obf, Obf, Wo_w, Wo_w, Wo_w, Wo_b, Wo_b, Wo_b, out, out, out);
}

// Round 14
// 215.189 us; speedup vs baseline: 1.0482x; 1.0095x over previous
//
#include <hip/hip_runtime.h>
#include <hip/hip_bf16.h>

typedef __attribute__((ext_vector_type(8))) short short8;
typedef __attribute__((ext_vector_type(4))) float f32x4;
typedef unsigned short us;

#define MFMA16(a,b,c) __builtin_amdgcn_mfma_f32_16x16x32_bf16((a),(b),(c),0,0,0)
#define LOG2E 1.4426950408889634f

static __device__ __forceinline__ us bf16r(float x){
  unsigned u = __builtin_bit_cast(unsigned, x);
  u = u + 0x7fffu + ((u >> 16) & 1u);
  return (us)(u >> 16);
}
static __device__ __forceinline__ unsigned cvtpk(float a, float b){
  unsigned r; asm("v_cvt_pk_bf16_f32 %0, %1, %2" : "=v"(r) : "v"(a), "v"(b)); return r;
}
static __device__ __forceinline__ short8 cvt8(float4 a, float4 b){
  uint4 u; u.x = cvtpk(a.x, a.y); u.y = cvtpk(a.z, a.w);
  u.z = cvtpk(b.x, b.y); u.w = cvtpk(b.z, b.w);
  return __builtin_bit_cast(short8, u);
}
static __device__ __forceinline__ float b2f(us h){
  return __builtin_bit_cast(float, (unsigned)h << 16);
}
static __device__ __forceinline__ float exp2fast(float x){
  float r; asm("v_exp_f32 %0, %1" : "=v"(r) : "v"(x)); return r;
}
static __device__ __forceinline__ float rcpfast(float x){
  float r; asm("v_rcp_f32 %0, %1" : "=v"(r) : "v"(x)); return r;
}
static __device__ __forceinline__ float fractfast(float x){
  float r; asm("v_fract_f32 %0, %1" : "=v"(r) : "v"(x)); return r;
}
// x += dpp_move(x); ctrl/row_mask are template constants (builtin needs immediates).
template<int CTRL, int RMASK>
static __device__ __forceinline__ float dpp_add(float x){
  int t = __builtin_amdgcn_update_dpp(0, __builtin_bit_cast(int, x), CTRL, RMASK, 0xf, false);
  return x + __builtin_bit_cast(float, t);
}
// 64-lane inclusive add-scan, pure VALU (6 DPP ops):
// row_shr 1/2/4/8, row_bcast:15 (rows 1,3), row_bcast:31 (rows 2,3)
static __device__ __forceinline__ float wave_iscan(float x){
  x = dpp_add<0x111, 0xf>(x);
  x = dpp_add<0x112, 0xf>(x);
  x = dpp_add<0x114, 0xf>(x);
  x = dpp_add<0x118, 0xf>(x);
  x = dpp_add<0x142, 0xa>(x);
  x = dpp_add<0x143, 0xc>(x);
  return x;
}
static __device__ __forceinline__ float lane63(float x){
  return __builtin_bit_cast(float, __builtin_amdgcn_readlane(__builtin_bit_cast(int, x), 63));
}

// ---------------- pos_emb [64d][64n] fp32 -> peT [64n][64d] bf16, pre-scaled by log2(e) ----
__global__ __launch_bounds__(256)
void transpose_pe(const float* __restrict__ pe, us* __restrict__ peT){
  const int t = threadIdx.x;
  const int n = t & 63, dq = t >> 6;
#pragma unroll
  for (int j = 0; j < 16; ++j){
    const int d = dq * 16 + j;
    peT[n * 64 + d] = bf16r(pe[d * 64 + n] * LOG2E);
  }
}

// ---------------- V bf16 [4096][1024] -> VT bf16 [b][h][64d][1024s] ----------------
__global__ __launch_bounds__(256)
void transpose_v(const us* __restrict__ Vb, us* __restrict__ VT){
  __shared__ __align__(16) us tile[64 * 72];
  const int t = threadIdx.x;
  const int stile = blockIdx.x & 15;
  const int bh = blockIdx.x >> 4;
  const int b = bh >> 4, h = bh & 15;
  const int s0 = stile << 6;
#pragma unroll
  for (int c = 0; c < 2; ++c){
    const int idx = t + (c << 8);
    const int sr = idx >> 3, cw = idx & 7;
    *(short8*)&tile[sr * 72 + cw * 8] =
        *(const short8*)(Vb + ((size_t)(b * 1024 + s0 + sr)) * 1024 + h * 64 + cw * 8);
  }
  __syncthreads();
#pragma unroll
  for (int c = 0; c < 2; ++c){
    const int idx = t + (c << 8);
    const int dr = idx >> 3, sw = idx & 7;
    short8 o;
#pragma unroll
    for (int j = 0; j < 8; ++j) o[j] = (short)tile[(sw * 8 + j) * 72 + dr];
    *(short8*)(VT + ((size_t)(bh * 64 + dr)) * 1024 + s0 + sw * 8) = o;
  }
}

// ---------------- GEMM: C[4096][1024] = A[4096][1024] @ W[1024][1024]^T + bias ----------
template<bool A_BF16, bool OUT_BF16>
__global__ __launch_bounds__(256)
void gemm3(const void* __restrict__ Av0, const void* __restrict__ Av1, const void* __restrict__ Av2,
           const float* __restrict__ W0, const float* __restrict__ W1, const float* __restrict__ W2,
           const float* __restrict__ bp0, const float* __restrict__ bp1, const float* __restrict__ bp2,
           void* __restrict__ O0, void* __restrict__ O1, void* __restrict__ O2){
  __shared__ __align__(16) us Al[128 * 64];
  __shared__ __align__(16) us Bl[128 * 64];
  const int sel = blockIdx.y;
  const void* Av   = sel == 0 ? Av0 : (sel == 1 ? Av1 : Av2);
  const float* Wm  = sel == 0 ? W0  : (sel == 1 ? W1  : W2);
  const float* bias = sel == 0 ? bp0 : (sel == 1 ? bp1 : bp2);
  void* Ov         = sel == 0 ? O0  : (sel == 1 ? O1  : O2);
  const int tid = threadIdx.x;
  const int bm = blockIdx.x & 31, bn = blockIdx.x >> 5;
  const int m0 = bm << 7, n0 = bn << 7;
  const int w = tid >> 6, l = tid & 63;
  const int lr = l & 15, lg = l >> 4;
  const int wm = (w & 1) << 6, wn = (w >> 1) << 6;
  int srow[4], scol[4], sdst[4];
#pragma unroll
  for (int c = 0; c < 4; ++c){
    const int idx = tid + (c << 8);
    const int r = idx >> 3, cw = idx & 7;
    srow[c] = r; scol[c] = cw << 3;
    sdst[c] = r * 64 + ((cw << 3) ^ ((r & 7) << 3));
  }
  const int swz = (lr & 7) << 3;
  f32x4 acc[4][4];
#pragma unroll
  for (int i = 0; i < 4; ++i)
#pragma unroll
    for (int j = 0; j < 4; ++j) acc[i][j] = (f32x4){0.f, 0.f, 0.f, 0.f};

  auto ldA = [&](int c, int k) -> short8 {
    if constexpr (A_BF16){
      return *(const short8*)((const us*)Av + (size_t)(m0 + srow[c]) * 1024 + k + scol[c]);
    } else {
      const float* p = (const float*)Av + (size_t)(m0 + srow[c]) * 1024 + k + scol[c];
      return cvt8(*(const float4*)p, *(const float4*)(p + 4));
    }
  };
  auto ldW = [&](int c, int k) -> short8 {
    const float* p = Wm + (size_t)(n0 + srow[c]) * 1024 + k + scol[c];
    return cvt8(*(const float4*)p, *(const float4*)(p + 4));
  };

  short8 av[4], bv[4];
#pragma unroll
  for (int c = 0; c < 4; ++c){ av[c] = ldA(c, 0); bv[c] = ldW(c, 0); }

  for (int k0 = 0; k0 < 1024; k0 += 64){
    __syncthreads();
#pragma unroll
    for (int c = 0; c < 4; ++c){
      *(short8*)&Al[sdst[c]] = av[c];
      *(short8*)&Bl[sdst[c]] = bv[c];
    }
    __syncthreads();
    if (k0 < 960){
#pragma unroll
      for (int c = 0; c < 4; ++c){ av[c] = ldA(c, k0 + 64); bv[c] = ldW(c, k0 + 64); }
    }
#pragma unroll
    for (int ks = 0; ks < 2; ++ks){
      short8 af[4], bfv[4];
#pragma unroll
      for (int mt = 0; mt < 4; ++mt)
        af[mt] = *(const short8*)&Al[(wm + mt * 16 + lr) * 64 + (((ks << 5) + (lg << 3)) ^ swz)];
#pragma unroll
      for (int nt = 0; nt < 4; ++nt)
        bfv[nt] = *(const short8*)&Bl[(wn + nt * 16 + lr) * 64 + (((ks << 5) + (lg << 3)) ^ swz)];
#pragma unroll
      for (int mt = 0; mt < 4; ++mt)
#pragma unroll
        for (int nt = 0; nt < 4; ++nt)
          acc[mt][nt] = MFMA16(af[mt], bfv[nt], acc[mt][nt]);
    }
  }
  float bb[4];
#pragma unroll
  for (int nt = 0; nt < 4; ++nt) bb[nt] = bias[n0 + wn + nt * 16 + lr];
#pragma unroll
  for (int mt = 0; mt < 4; ++mt)
#pragma unroll
    for (int nt = 0; nt < 4; ++nt)
#pragma unroll
      for (int r = 0; r < 4; ++r){
        const size_t m = m0 + wm + mt * 16 + lg * 4 + r;
        const size_t n = n0 + wn + nt * 16 + lr;
        const float vv = acc[mt][nt][r] + bb[nt];
        if (OUT_BF16) ((us*)Ov)[m * 1024 + n] = bf16r(vv);
        else          ((float*)Ov)[m * 1024 + n] = vv;
      }
}

// ---------------- fused CoPE attention v13: v12 + XCD-locality block swizzle ------
// All 64 q-tile blocks of one (b,h) land on ONE XCD: K+V working set per XCD =
// 8 heads x 256KB = 2MB < 4MB L2. Serial K/V load chains hit L2 (~200cyc) not
// HBM (~900cyc). wg = (orig&7)*512 + orig/8 is bijective (4096 = 8*512).
__global__ __launch_bounds__(256, 4)
void cope_attn_v13(const us* __restrict__ Qb, const us* __restrict__ Kb,
                   const us* __restrict__ VT, const us* __restrict__ peT,
                   us* __restrict__ Ob){
  __shared__ __align__(16) us yl[16 * 512];   // 16 KB: li temp, then per-chunk y/P
  __shared__ float sums[16];
  const int tid = threadIdx.x;
  const int w = tid >> 6, l = tid & 63;
  const int lr = l & 15, lg = l >> 4;
  const int wg = ((blockIdx.x & 7) << 9) | (blockIdx.x >> 3);  // XCD swizzle
  const int qt = wg & 63;
  const int bh = wg >> 6;
  const int b = bh >> 4, h = bh & 15;
  const int q0 = qt << 4;
  const us* Qh = Qb + ((size_t)(b * 1024 + q0)) * 1024 + h * 64;
  const us* Kh = Kb + ((size_t)(b * 1024)) * 1024 + h * 64;
  const us* Vh = VT + ((size_t)bh) * 64 * 1024;
  const float QSC = 0.125f * LOG2E;

  const short8 aq0 = *(const short8*)(Qh + (size_t)lr * 1024 + lg * 8);
  const short8 aq1 = *(const short8*)(Qh + (size_t)lr * 1024 + 32 + lg * 8);

  // 1) li[q][n] = (Q . pos_emb)*log2e ; wave w owns n-tile [16w,16w+16) -> bf16 temp
  {
    f32x4 a = (f32x4){0.f, 0.f, 0.f, 0.f};
    const short8 p0 = *(const short8*)(peT + (size_t)(w * 16 + lr) * 64 + lg * 8);
    const short8 p1 = *(const short8*)(peT + (size_t)(w * 16 + lr) * 64 + 32 + lg * 8);
    a = MFMA16(aq0, p0, a);
    a = MFMA16(aq1, p1, a);
#pragma unroll
    for (int r = 0; r < 4; ++r) yl[(lg * 4 + r) * 64 + w * 16 + lr] = bf16r(a[r]);
  }
  __syncthreads();
  // 2) per-row register tables: lane n holds {li[n] (lo16), li[n+1]-li[n] (hi16)}
  unsigned trow[4];
#pragma unroll
  for (int rr = 0; rr < 4; ++rr){
    const int row = w * 4 + rr;
    const us lov = yl[row * 64 + l];
    const us hiv = (l < 63) ? yl[row * 64 + l + 1] : lov;
    const float dif = b2f(hiv) - b2f(lov);
    trow[rr] = (unsigned)lov | ((unsigned)bf16r(dif) << 16);
  }

  float carry[4] = {0.f, 0.f, 0.f, 0.f};
  f32x4 oacc = (f32x4){0.f, 0.f, 0.f, 0.f};
  const int d0 = w * 16;
  const int psw = lr & 7;

  for (int c = 1; c >= 0; --c){
    const int koff = c << 9;
    __syncthreads();   // yl free (after trow setup / after prev PV)
    // 3) QK^T * QSC -> bf16 yl[16][512] granule-swizzled; wave keys [128w,128w+128)
    {
      const int kbase = w << 7;
      const us* Kw = Kh + (size_t)(koff + kbase + lr) * 1024 + lg * 8;
      for (int t = 0; t < 8; ++t){
        const short8 b0 = *(const short8*)(Kw + (size_t)(t * 16) * 1024);
        const short8 b1 = *(const short8*)(Kw + (size_t)(t * 16) * 1024 + 32);
        f32x4 a = (f32x4){0.f, 0.f, 0.f, 0.f};
        a = MFMA16(aq0, b0, a);
        a = MFMA16(aq1, b1, a);
        const int kc = kbase + t * 16 + lr;
        const unsigned p01 = cvtpk(a[0] * QSC, a[1] * QSC);
        const unsigned p23 = cvtpk(a[2] * QSC, a[3] * QSC);
        const int r0 = lg * 4;
        yl[(r0 + 0) * 512 + (((kc >> 3) ^ ((r0 + 0) & 7)) << 3) + (kc & 7)] = (us)p01;
        yl[(r0 + 1) * 512 + (((kc >> 3) ^ ((r0 + 1) & 7)) << 3) + (kc & 7)] = (us)(p01 >> 16);
        yl[(r0 + 2) * 512 + (((kc >> 3) ^ ((r0 + 2) & 7)) << 3) + (kc & 7)] = (us)p23;
        yl[(r0 + 3) * 512 + (((kc >> 3) ^ ((r0 + 3) & 7)) << 3) + (kc & 7)] = (us)(p23 >> 16);
      }
    }
    __syncthreads();
    // 4) CoPE + unnormalized exp2; wave w owns rows [4w,4w+4); lane owns cols [8l,8l+8)
#pragma unroll
    for (int rr = 0; rr < 4; ++rr){
      const int row = w * 4 + rr;
      const int ad = row * 512 + ((l ^ (row & 7)) << 3);
      const short8 y0 = *(const short8*)&yl[ad];
      float x[8];
#pragma unroll
      for (int j = 0; j < 8; ++j) x[j] = b2f((us)y0[j]);
      float sum = 0.f;
      if (c == 0 && carry[rr] >= 63.f){
        // all chunk-0 positions clamp to 63: interp == li[row][63] uniformly
        const float li63 = b2f((us)(unsigned)__builtin_amdgcn_readlane((int)trow[rr], 63));
#pragma unroll
        for (int i = 0; i < 8; ++i){
          const float e = exp2fast(x[i] + li63);
          x[i] = e;
          sum += e;
        }
      } else {
        // 8 independent sigmoids (trans-pipe pipelined), then depth-3 tree prefix
        float g[8];
#pragma unroll
        for (int i = 0; i < 8; ++i) g[i] = rcpfast(1.f + exp2fast(-x[i]));
        const float a1 = g[0] + g[1];
        const float a3 = g[2] + g[3];
        const float a5 = g[4] + g[5];
        const float a7 = g[6] + g[7];
        const float b2v = g[2] + a1;
        const float b3v = a3 + a1;
        const float i4 = g[4] + b3v;
        const float i5 = a5 + b3v;
        const float i6 = g[6] + a5 + b3v;
        const float s  = a7 + a5 + b3v;     // inclusive total of this lane's 8 gates
        float pref[8];
        pref[0] = 0.f;  pref[1] = g[0]; pref[2] = a1;  pref[3] = b2v;
        pref[4] = b3v;  pref[5] = i4;   pref[6] = i5;  pref[7] = i6;
        // DPP wave scan (VALU-only)
        const float run = wave_iscan(s);
        const float T = lane63(run);
        const float base = carry[rr] + T - (run - s);   // suffix base incl. higher chunks
        carry[rr] += T;
        const unsigned tbl = trow[rr];
#pragma unroll
        for (int i = 0; i < 8; ++i){
          float p = base - pref[i];
          p = __builtin_amdgcn_fmed3f(p, 0.f, 63.f);
          const int il = (int)p;
          const float wt = fractfast(p);
          const unsigned pr = (unsigned)__builtin_amdgcn_ds_bpermute(il << 2, (int)tbl);
          const float lo  = __builtin_bit_cast(float, pr << 16);
          const float dif = __builtin_bit_cast(float, pr & 0xffff0000u);
          const float e = exp2fast(x[i] + lo + wt * dif);
          x[i] = e;
          sum += e;
        }
      }
      const float rs = lane63(wave_iscan(sum));   // row total via DPP reduce
      if (l == 0){
        if (c == 1) sums[row] = rs;
        else        sums[row] += rs;   // same lane wrote chunk 1: no race
      }
      uint4 ua;
      ua.x = cvtpk(x[0], x[1]); ua.y = cvtpk(x[2], x[3]);
      ua.z = cvtpk(x[4], x[5]); ua.w = cvtpk(x[6], x[7]);
      *(uint4*)&yl[ad] = ua;    // in place: lane writes exactly what it read
    }
    __syncthreads();
    // 5) PV accumulate: wave w owns d-tile [16w,16w+16)
    {
      const us* Vw = Vh + (size_t)(d0 + lr) * 1024 + koff + lg * 8;
      for (int ks = 0; ks < 16; ++ks){
        const short8 vb = *(const short8*)(Vw + ks * 32);
        const short8 pa = *(const short8*)&yl[lr * 512 + ((((ks << 2) + lg) ^ psw) << 3)];
        oacc = MFMA16(pa, vb, oacc);
      }
    }
  }
  __syncthreads();   // sums visible
#pragma unroll
  for (int r = 0; r < 4; ++r){
    const float inv = rcpfast(sums[lg * 4 + r]);
    Ob[((size_t)(b * 1024 + q0 + lg * 4 + r)) * 1024 + h * 64 + d0 + lr] = bf16r(oacc[r] * inv);
  }
}

extern "C" void kernel_launch(void* const* d_in, const int* in_sizes, int n_in,
                              void* d_out, int out_size, void* d_ws, size_t ws_size,
                              hipStream_t stream) {
  const float* q    = (const float*)d_in[0];
  const float* k    = (const float*)d_in[1];
  const float* v    = (const float*)d_in[2];
  const float* Wq_w = (const float*)d_in[3];
  const float* Wq_b = (const float*)d_in[4];
  const float* Wk_w = (const float*)d_in[5];
  const float* Wk_b = (const float*)d_in[6];
  const float* Wv_w = (const float*)d_in[7];
  const float* Wv_b = (const float*)d_in[8];
  const float* Wo_w = (const float*)d_in[9];
  const float* Wo_b = (const float*)d_in[10];
  const float* pe   = (const float*)d_in[11];
  float* out = (float*)d_out;

  char* W = (char*)d_ws;
  const size_t MB = (size_t)1 << 20;
  us* Qbf = (us*)(W);
  us* Kbf = (us*)(W + 8 * MB);
  us* Vbf = (us*)(W + 16 * MB);
  us* VTb = (us*)(W + 24 * MB);
  us* Obf = (us*)(W + 32 * MB);
  us* peT = (us*)(W + 40 * MB);

  transpose_pe<<<1, 256, 0, stream>>>(pe, peT);
  gemm3<false, true><<<dim3(256, 3), 256, 0, stream>>>(
      q, k, v, Wq_w, Wk_w, Wv_w, Wq_b, Wk_b, Wv_b, Qbf, Kbf, Vbf);
  transpose_v<<<1024, 256, 0, stream>>>(Vbf, VTb);
  cope_attn_v13<<<4096, 256, 0, stream>>>(Qbf, Kbf, VTb, peT, Obf);
  gemm3<true, false><<<dim3(256, 1), 256, 0, stream>>>(
      Obf, Obf, Obf, Wo_w, Wo_w, Wo_w, Wo_b, Wo_b, Wo_b, out, out, out);
}